// Round 22
// baseline (141.315 us; speedup 1.0000x reference)
//
#include <hip/hip_runtime.h>

using bf16 = __bf16;
typedef __attribute__((ext_vector_type(8))) __bf16 bf16x8;
typedef __attribute__((ext_vector_type(4))) float f32x4;

#define HID    768
#define S_TOT  1728
#define MLP_   3072
#define NFUSED 5376   /* MLP + 3*HID */
#define HEADS  12
#define HDIM   64
#define ROT    48
#define KCAT   2304   /* HID + MLP/2 : merged attn-out/FF GEMM K */
#define NQKV   2304   /* q|k|v compact buffer width */

// ---- async global->LDS, 16B per lane. LDS dst is wave-uniform base; HW adds lane*16.
__device__ __forceinline__ void gload16(const void* g, void* l) {
  __builtin_amdgcn_global_load_lds((__attribute__((address_space(1))) void*)g,
                                   (__attribute__((address_space(3))) void*)l,
                                   16, 0, 0);
}

// native 2^x : raw v_exp_f32 (exp2f w/o fast-math takes OCML's correction path, ~15 cyc extra)
__device__ __forceinline__ float fexp2(float x) {
  float r; asm("v_exp_f32 %0, %1" : "=v"(r) : "v"(x)); return r;
}

// pack two f32 -> 2 bf16 in one u32 (lo = src0)
__device__ __forceinline__ unsigned int cvtpk(float lo, float hi) {
  unsigned int r;
  asm("v_cvt_pk_bf16_f32 %0, %1, %2" : "=v"(r) : "v"(lo), "v"(hi));
  return r;
}

__device__ __forceinline__ float wsum64(float v) {
  #pragma unroll
  for (int d = 32; d; d >>= 1) v += __shfl_xor(v, d);
  return v;
}

// ---------------- weights fp32 -> bf16, x/gate-interleaved + K-concat ----------------
__global__ __launch_bounds__(256) void k_conv(const float* __restrict__ wf,
    const float* __restrict__ wa, const float* __restrict__ wff,
    const float* __restrict__ bfu,
    bf16* __restrict__ owf, bf16* __restrict__ wcat, float* __restrict__ bperm) {
  int i = blockIdx.x * 256 + threadIdx.x;
  const int nf = NFUSED * HID, na = HID * HID, nff = HID * (MLP_ / 2);
  auto perm = [](int o) {
    if (o < 1536) return (o >> 4) * 32 + (o & 15);
    if (o < 3072) { int g = o - 1536; return (g >> 4) * 32 + 16 + (g & 15); }
    return o;
  };
  if (i < nf) {
    int o = i / HID, c = i % HID;
    owf[(size_t)perm(o) * HID + c] = (bf16)wf[i];
  }
  if (i < NFUSED) bperm[perm(i)] = bfu[i];
  if (i < na)  wcat[(i / HID) * KCAT + (i % HID)] = (bf16)wa[i];
  if (i < nff) wcat[(i / (MLP_ / 2)) * KCAT + HID + (i % (MLP_ / 2))] = (bf16)wff[i];
}

// ---------------- per-(b,c) RMS over spatial ----------------
__global__ __launch_bounds__(256) void k_rms(const float* __restrict__ x,
    const float* __restrict__ w, float* __restrict__ scale) {
  int bc = blockIdx.x;                       // 0..1535
  const float* xp = x + (size_t)bc * S_TOT;
  float s = 0.f;
  for (int i = threadIdx.x; i < S_TOT; i += 256) { float v = xp[i]; s += v * v; }
  s = wsum64(s);
  __shared__ float red[4];
  int lane = threadIdx.x & 63, wv = threadIdx.x >> 6;
  if (lane == 0) red[wv] = s;
  __syncthreads();
  if (threadIdx.x == 0) {
    float t = red[0] + red[1] + red[2] + red[3];
    scale[bc] = w[bc % HID] * rsqrtf(t * (1.f / S_TOT) + 1e-6f);
  }
}

// ---------------- normalize + transpose (B,C,S) -> (B*S, C) bf16 ----------------
__global__ __launch_bounds__(256) void k_xpose(const float* __restrict__ x,
    const float* __restrict__ scale, bf16* __restrict__ xn) {
  __shared__ float t[32][33];
  int b = blockIdx.z, st = blockIdx.x * 32, ct = blockIdx.y * 32;
  int tx = threadIdx.x & 31, ty = threadIdx.x >> 5;
  #pragma unroll
  for (int i = 0; i < 4; ++i) {
    int c = ct + ty + i * 8;
    t[ty + i * 8][tx] = x[((size_t)b * HID + c) * S_TOT + st + tx] * scale[b * HID + c];
  }
  __syncthreads();
  #pragma unroll
  for (int i = 0; i < 4; ++i) {
    int s = st + ty + i * 8;
    xn[((size_t)b * S_TOT + s) * HID + ct + tx] = (bf16)t[tx][ty + i * 8];
  }
}

// ---------------- RoPE cos/sin tables (S,48) ----------------
__global__ __launch_bounds__(256) void k_rope(float* __restrict__ ct, float* __restrict__ st) {
  int i = blockIdx.x * 256 + threadIdx.x;
  if (i >= S_TOT * ROT) return;
  int s = i / ROT, j = i % ROT;
  int axis = j >> 4, pr = (j & 15) >> 1;
  float base = 3.14159265358979323846f * (1.f + pr * (127.f / 7.f));
  int coord = axis == 0 ? (s / 144) : axis == 1 ? ((s / 12) % 12) : (s % 12);
  float pos = -1.f + coord * (2.f / 11.f);
  float f = pos * base;
  ct[i] = cosf(f); st[i] = sinf(f);
}

// ---------------- QKV GEMM (ACCEPTED, R14/R16-proven): BM=128, BN=192, BK=32, 2-buf ----------------
__global__ __launch_bounds__(256, 3) void k_gemmF(const bf16* __restrict__ A,
    const bf16* __restrict__ Bw, const float* __restrict__ bias,
    bf16* __restrict__ acat, bf16* __restrict__ qkvb, int M, int N, int K) {
  extern __shared__ __align__(16) char smem[];
  bf16* aL = (bf16*)smem;                       // 2 bufs x 128x32
  bf16* bL = (bf16*)(smem + 2 * 8192);          // 2 bufs x 192x32
  constexpr int BN = 192, NT = 6;
  const int nT = K / 32;
  int nwg = gridDim.x;
  int cq = nwg >> 3, crr = nwg & 7;
  int xcd = blockIdx.x & 7, pos = blockIdx.x >> 3;
  int idx = (xcd < crr ? xcd * (cq + 1) : crr * (cq + 1) + (xcd - crr) * cq) + pos;
  int nmt = M / 128;
  int n0 = (idx / nmt) * BN, m0 = (idx % nmt) * 128;
  int lane = threadIdx.x & 63, wv = threadIdx.x >> 6;
  int wm = (wv >> 1) * 64, wn = (wv & 1) * (BN / 2);
  int arow = lane >> 2;
  int acs = ((lane & 3) ^ ((lane >> 3) & 3)) * 8;   // T2 pre-swizzled source chunk
  int r16 = lane & 15, g8 = (lane >> 4) * 8;
  int swz = ((r16 >> 1) & 3) << 3;                  // T2 read-side XOR
  const bf16* Ag = A + (size_t)m0 * K;
  const bf16* Bg = Bw + (size_t)n0 * K;
  auto stage = [&](int p, int t) {
    int kk = t * 32;
    #pragma unroll
    for (int i = 0; i < 2; ++i) {
      int rb = wv * 32 + i * 16;
      gload16(Ag + (size_t)(rb + arow) * K + kk + acs, aL + p * 4096 + rb * 32);
    }
    #pragma unroll
    for (int i = 0; i < 3; ++i) {
      int rb = wv * 48 + i * 16;
      gload16(Bg + (size_t)(rb + arow) * K + kk + acs, bL + p * (BN * 32) + rb * 32);
    }
  };
  f32x4 acc[4][NT] = {};
  int p = 0;
  stage(0, 0);
  for (int t = 0; t < nT; ++t) {
    if (t + 1 < nT) {
      stage(p ^ 1, t + 1);
      asm volatile("s_waitcnt vmcnt(5)\ns_barrier" ::: "memory");
    } else {
      asm volatile("s_waitcnt vmcnt(0)\ns_barrier" ::: "memory");
    }
    bf16x8 af[4];
    #pragma unroll
    for (int mi = 0; mi < 4; ++mi)
      af[mi] = *(const bf16x8*)(aL + p * 4096 + (wm + mi * 16 + r16) * 32 + (g8 ^ swz));
    __builtin_amdgcn_s_setprio(1);
    #pragma unroll
    for (int ni = 0; ni < NT; ++ni) {
      bf16x8 bfr = *(const bf16x8*)(bL + p * (BN * 32) + (wn + ni * 16 + r16) * 32 + (g8 ^ swz));
      #pragma unroll
      for (int mi = 0; mi < 4; ++mi)
        acc[mi][ni] = __builtin_amdgcn_mfma_f32_16x16x32_bf16(af[mi], bfr, acc[mi][ni], 0, 0, 0);
    }
    __builtin_amdgcn_s_setprio(0);
    asm volatile("s_barrier" ::: "memory");   // readers done before restage
    p ^= 1;
  }
  int cr = (lane >> 4) * 4;
  if (n0 < MLP_) {
    // interleaved x/gate: frag pair (2p, 2p+1) -> 16 ff channels each
    #pragma unroll
    for (int pp = 0; pp < 3; ++pp) {
      int base = n0 + wn + pp * 32;
      int ch = (base >> 5) * 16 + r16;
      float bx = bias[base + r16], bg = bias[base + 16 + r16];
      #pragma unroll
      for (int mi = 0; mi < 4; ++mi)
        #pragma unroll
        for (int j = 0; j < 4; ++j) {
          int row = m0 + wm + mi * 16 + cr + j;
          float xv = acc[mi][2 * pp][j] + bx;
          float gv = acc[mi][2 * pp + 1][j] + bg;
          float sg = gv / (1.f + fexp2(gv * -1.442695041f));
          acat[(size_t)row * KCAT + HID + ch] = (bf16)(sg * xv);
        }
    }
  } else {
    #pragma unroll
    for (int mi = 0; mi < 4; ++mi)
      #pragma unroll
      for (int ni = 0; ni < NT; ++ni) {
        int col = n0 + wn + ni * 16 + r16;
        float bv = bias[col];
        #pragma unroll
        for (int j = 0; j < 4; ++j) {
          int row = m0 + wm + mi * 16 + cr + j;
          qkvb[(size_t)row * NQKV + (col - MLP_)] = (bf16)(acc[mi][ni][j] + bv);
        }
      }
  }
}

// ---------------- merged GEMM (R18-proven): BM=128, BN=64, BK=64, 2-buf, 36 iters ----------------
__global__ __launch_bounds__(256, 3) void k_gemmO(const bf16* __restrict__ A,
    const bf16* __restrict__ Bw, const float* __restrict__ bias,
    float* __restrict__ Out, const float* __restrict__ X, int M, int N, int K) {
  extern __shared__ __align__(16) char smem[];
  bf16* aL = (bf16*)smem;                       // 2 bufs x 128x64 (16384 B each)
  bf16* bL = (bf16*)(smem + 2 * 16384);         // 2 bufs x 64x64  (8192 B each)
  const int nT = K / 64;                        // 36
  int nwg = gridDim.x;
  int cq = nwg >> 3, crr = nwg & 7;
  int xcd = blockIdx.x & 7, pos = blockIdx.x >> 3;
  int idx = (xcd < crr ? xcd * (cq + 1) : crr * (cq + 1) + (xcd - crr) * cq) + pos;
  int ntn = N / 64;
  int m0 = (idx / ntn) * 128, n0 = (idx % ntn) * 64;   // m-major (A-panel locality)
  int lane = threadIdx.x & 63, wv = threadIdx.x >> 6;
  int wm = (wv >> 1) * 64, wn = (wv & 1) * 32;
  int rg = lane >> 3, ch = lane & 7;            // staging: 8 rows x 8 chunks per 1KB issue
  int scs = (ch ^ rg) * 8;                      // pre-swizzled source elem offset
  int r16 = lane & 15, g8 = (lane >> 4) * 8;    // fragment addressing
  const bf16* Ag = A + (size_t)m0 * K;
  const bf16* Bg = Bw + (size_t)n0 * K;
  auto stage = [&](int p, int t) {
    int kk = t * 64;
    #pragma unroll
    for (int i = 0; i < 4; ++i) {
      int rb = wv * 32 + i * 8;
      gload16(Ag + (size_t)(rb + rg) * K + kk + scs, aL + p * 8192 + rb * 64);
    }
    #pragma unroll
    for (int i = 0; i < 2; ++i) {
      int rb = wv * 16 + i * 8;
      gload16(Bg + (size_t)(rb + rg) * K + kk + scs, bL + p * 4096 + rb * 64);
    }
  };
  f32x4 acc[4][2] = {};
  int p = 0;
  stage(0, 0);
  for (int t = 0; t < nT; ++t) {
    if (t + 1 < nT) {
      stage(p ^ 1, t + 1);
      asm volatile("s_waitcnt vmcnt(6)\ns_barrier" ::: "memory");
    } else {
      asm volatile("s_waitcnt vmcnt(0)\ns_barrier" ::: "memory");
    }
    bf16x8 af[4][2], bfr[2][2];
    #pragma unroll
    for (int kc = 0; kc < 2; ++kc) {
      int ce = ((kc * 4 + (lane >> 4)) ^ (r16 & 7)) * 8;   // swizzled chunk, elems
      #pragma unroll
      for (int mi = 0; mi < 4; ++mi)
        af[mi][kc] = *(const bf16x8*)(aL + p * 8192 + (wm + mi * 16 + r16) * 64 + ce);
      #pragma unroll
      for (int ni = 0; ni < 2; ++ni)
        bfr[ni][kc] = *(const bf16x8*)(bL + p * 4096 + (wn + ni * 16 + r16) * 64 + ce);
    }
    __builtin_amdgcn_s_setprio(1);
    #pragma unroll
    for (int kc = 0; kc < 2; ++kc)
      #pragma unroll
      for (int mi = 0; mi < 4; ++mi)
        #pragma unroll
        for (int ni = 0; ni < 2; ++ni)
          acc[mi][ni] = __builtin_amdgcn_mfma_f32_16x16x32_bf16(af[mi][kc], bfr[ni][kc], acc[mi][ni], 0, 0, 0);
    __builtin_amdgcn_s_setprio(0);
    asm volatile("s_barrier" ::: "memory");
    p ^= 1;
  }
  // transpose via padded LDS, then coalesced store along s with residual
  int cr = (lane >> 4) * 4;
  float* tb = (float*)smem;                    // [64][stride 129]
  __syncthreads();
  #pragma unroll
  for (int mi = 0; mi < 4; ++mi)
    #pragma unroll
    for (int ni = 0; ni < 2; ++ni) {
      int c = wn + ni * 16 + r16;
      float bv = bias[n0 + c];
      #pragma unroll
      for (int j = 0; j < 4; ++j)
        tb[c * 129 + wm + mi * 16 + cr + j] = acc[mi][ni][j] + bv;
    }
  __syncthreads();
  for (int ci = 0; ci < 16; ++ci) {
    int c = wv * 16 + ci;
    #pragma unroll
    for (int si = 0; si < 2; ++si) {
      int r = si * 64 + lane;
      int m = m0 + r;
      int bb = (m >= S_TOT) ? 1 : 0;
      size_t oidx = ((size_t)bb * HID + n0 + c) * S_TOT + (m - bb * S_TOT);
      Out[oidx] = tb[c * 129 + r] + X[oidx];
    }
  }
}

// ---------------- per-head LN + RoPE on q,k; v -> transposed layout ----------------
__global__ __launch_bounds__(256) void k_qkv(const bf16* __restrict__ qkvb,
    const float* __restrict__ ct, const float* __restrict__ st,
    const float* __restrict__ qg, const float* __restrict__ qb,
    const float* __restrict__ kg, const float* __restrict__ kb,
    bf16* __restrict__ qr, bf16* __restrict__ kr, bf16* __restrict__ vt) {
  int bs = blockIdx.x;                    // b*1728 + s
  int b = bs / S_TOT, s = bs % S_TOT;
  int lane = threadIdx.x & 63, wv = threadIdx.x >> 6;
  int d = lane;
  float c = 0.f, sn = 0.f;
  if (d < ROT) { c = ct[s * ROT + d]; sn = st[s * ROT + d]; }
  for (int it = 0; it < 9; ++it) {
    int rr = wv * 9 + it;                 // 0..35 = (tensor, head)
    int t = rr / HEADS, h = rr % HEADS;
    float v = (float)qkvb[(size_t)bs * NQKV + t * HID + h * HDIM + d];
    if (t < 2) {
      float s1 = v, s2 = v * v;           // paired mean/var reduction: one 6-step chain
      #pragma unroll
      for (int dd = 32; dd; dd >>= 1) { s1 += __shfl_xor(s1, dd); s2 += __shfl_xor(s2, dd); }
      float mu = s1 * (1.f / 64);
      float var = s2 * (1.f / 64) - mu * mu;
      float vn = (v - mu) * rsqrtf(var + 1e-5f);
      vn = (t == 0) ? (vn * qg[d] + qb[d]) : (vn * kg[d] + kb[d]);
      float o = vn;
      if (d < ROT) {
        float p = __shfl_xor(vn, 1);
        float rot = (d & 1) ? p : -p;
        o = vn * c + rot * sn;
      }
      if (t == 0) o *= 0.18033688f;       // 0.125 * log2(e)
      bf16* dst = (t == 0) ? qr : kr;
      dst[((size_t)(b * HEADS + h) * S_TOT + s) * HDIM + d] = (bf16)o;
    } else {
      int sl = s & 63;
      int sp = (s & ~63) | ((sl & 15) << 2) | (sl >> 4);   // k' permutation
      vt[((size_t)(b * HEADS + h) * HDIM + d) * S_TOT + sp] = (bf16)v;
    }
  }
}

// ---------------- flash attention v4: T15 2-tile pipeline ----------------
// 4 waves x 16 q-rows, KV tile 64. Per iteration: issue QK^T(t+1) FIRST (reads
// kld[buf^1], independent MFMAs), then softmax(t) VALU runs in their shadow,
// then PV(t). Buffer lifetimes (one barrier/iter): kld[buf] (K(t)) last read
// iter t-1 -> restage K(t+2) there; vld[buf^1] (V(t-1)) last read iter t-1 ->
// restage V(t+1) there; vmcnt(0)+barrier at top of t+1 covers both (full-iter
// slack, L2-resident). T2 swizzle; T5 setprio; static-max exp2 softmax;
// packed P (k' perm shared with V). S_cur/S_next named arrays (static idx).
__global__ __launch_bounds__(256, 4) void k_attn(const bf16* __restrict__ qr,
    const bf16* __restrict__ kr, const bf16* __restrict__ vt, bf16* __restrict__ acat) {
  __shared__ __align__(16) bf16 kld[2][4096];
  __shared__ __align__(16) bf16 vld[2][4096];     // transposed: [d][k'], swizzled
  __shared__ __align__(16) bf16 pld[4][1024];     // per-wave 16x64 (k' cols), swizzled
  int rid = (blockIdx.x & 7) * 81 + (blockIdx.x >> 3);   // bijective (648 = 8*81)
  int bh = rid / 27, qt = rid % 27;
  int lane = threadIdx.x & 63, wv = threadIdx.x >> 6;
  int r16 = lane & 15, g8 = (lane >> 4) * 8;
  int sw = (r16 & 7) << 3;
  int lsw = (lane & 56) | ((lane ^ (lane >> 3)) & 7);
  const bf16* qbase = qr + ((size_t)bh * S_TOT + qt * 64 + wv * 16) * HDIM;
  bf16x8 qf[2];
  qf[0] = *(const bf16x8*)(qbase + r16 * HDIM + g8);
  qf[1] = *(const bf16x8*)(qbase + r16 * HDIM + 32 + g8);
  asm volatile("s_waitcnt vmcnt(0)" ::: "memory");      // q retired: vmcnt now only tracks stages
  const bf16* kg0 = kr + (size_t)bh * S_TOT * HDIM;
  const bf16* vg0 = vt + (size_t)bh * HDIM * S_TOT;
  auto stageK = [&](int bp, int kt) {
    #pragma unroll
    for (int i = 0; i < 2; ++i) {
      int q = wv * 2 + i;
      gload16(kg0 + (size_t)kt * 4096 + q * 512 + lsw * 8, &kld[bp][q * 512]);
    }
  };
  auto stageV = [&](int bp, int kt) {
    #pragma unroll
    for (int i = 0; i < 2; ++i) {
      int q = wv * 2 + i;
      gload16(vg0 + (size_t)(q * 8 + (lane >> 3)) * S_TOT + kt * 64 + (lsw & 7) * 8,
              &vld[bp][q * 512]);
    }
  };
  auto qkt = [&](int bp, f32x4* sa) {
    __builtin_amdgcn_s_setprio(1);
    #pragma unroll
    for (int nt = 0; nt < 4; ++nt) {
      sa[nt] = f32x4{0.f, 0.f, 0.f, 0.f};
      #pragma unroll
      for (int kc = 0; kc < 2; ++kc) {
        bf16x8 kf = *(const bf16x8*)(&kld[bp][(nt * 16 + r16) * 64 + ((kc * 32 + g8) ^ sw)]);
        sa[nt] = __builtin_amdgcn_mfma_f32_16x16x32_bf16(qf[kc], kf, sa[nt], 0, 0, 0);
      }
    }
    __builtin_amdgcn_s_setprio(0);
  };
  float l_part[4] = {0.f, 0.f, 0.f, 0.f};
  f32x4 acc_o[4] = {};
  f32x4 s_cur[4], s_nx[4];
  // prologue: K0,V0 -> buf0 (4 loads); K1 -> buf1 (2 loads); wait own first 4; barrier; QK^T(0)
  stageK(0, 0); stageV(0, 0);
  stageK(1, 1);
  asm volatile("s_waitcnt vmcnt(2)\ns_barrier" ::: "memory");
  qkt(0, s_cur);
  int buf = 0;
  for (int kt = 0; kt < 27; ++kt) {
    asm volatile("s_waitcnt vmcnt(0)\ns_barrier" ::: "memory");   // stages from iter kt-1 done; all waves past reads
    if (kt < 26) stageV(buf ^ 1, kt + 1);     // vld[buf^1]=V(kt-1), last read iter kt-1
    if (kt < 25) stageK(buf, kt + 2);         // kld[buf]=K(kt), last read iter kt-1
    if (kt < 26) qkt(buf ^ 1, s_nx);          // MFMA first: softmax VALU issues in its shadow
    // ---- static-max softmax on s_cur: P = exp2(logit), accumulate per-lane l ----
    #pragma unroll
    for (int j = 0; j < 4; ++j) {
      #pragma unroll
      for (int nt = 0; nt < 4; ++nt) {
        float pv = fexp2(s_cur[nt][j]);
        s_cur[nt][j] = pv;
        l_part[j] += pv;
      }
    }
    // ---- P -> LDS: k' columns 4*r16..4*r16+3, packed b64 writes (swizzled) ----
    #pragma unroll
    for (int j = 0; j < 4; ++j) {
      int rr = (lane >> 4) * 4 + j;
      unsigned int pa = cvtpk(s_cur[0][j], s_cur[1][j]);
      unsigned int pb = cvtpk(s_cur[2][j], s_cur[3][j]);
      unsigned long long pk = (unsigned long long)pa | ((unsigned long long)pb << 32);
      int off = rr * 64 + ((4 * r16) ^ ((rr & 7) << 3));
      *(unsigned long long*)(&pld[wv][off]) = pk;
    }
    // ---- PV(kt) (k' ordering shared by P and V) ----
    __builtin_amdgcn_s_setprio(1);
    #pragma unroll
    for (int nt = 0; nt < 4; ++nt)
      #pragma unroll
      for (int kc = 0; kc < 2; ++kc) {
        bf16x8 pf = *(const bf16x8*)(&pld[wv][r16 * 64 + ((kc * 32 + g8) ^ sw)]);
        bf16x8 vf = *(const bf16x8*)(&vld[buf][(nt * 16 + r16) * 64 + ((kc * 32 + g8) ^ sw)]);
        acc_o[nt] = __builtin_amdgcn_mfma_f32_16x16x32_bf16(pf, vf, acc_o[nt], 0, 0, 0);
      }
    __builtin_amdgcn_s_setprio(0);
    if (kt < 26) {
      #pragma unroll
      for (int nt = 0; nt < 4; ++nt) s_cur[nt] = s_nx[nt];
    }
    buf ^= 1;
  }
  int b = bh / HEADS, h = bh % HEADS;
  #pragma unroll
  for (int j = 0; j < 4; ++j) {
    float l = l_part[j];
    #pragma unroll
    for (int dd = 1; dd < 16; dd <<= 1) l += __shfl_xor(l, dd);
    float inv = 1.f / l;
    int s = qt * 64 + wv * 16 + (lane >> 4) * 4 + j;
    #pragma unroll
    for (int nt = 0; nt < 4; ++nt)
      acat[((size_t)b * S_TOT + s) * KCAT + h * HDIM + nt * 16 + r16] = (bf16)(acc_o[nt][j] * inv);
  }
}

extern "C" void kernel_launch(void* const* d_in, const int* in_sizes, int n_in,
                              void* d_out, int out_size, void* d_ws, size_t ws_size,
                              hipStream_t stream) {
  const float* x   = (const float*)d_in[0];
  const float* n1w = (const float*)d_in[1];
  const float* wf  = (const float*)d_in[2];
  const float* bfu = (const float*)d_in[3];
  const float* qg  = (const float*)d_in[4];
  const float* qb  = (const float*)d_in[5];
  const float* kg  = (const float*)d_in[6];
  const float* kb  = (const float*)d_in[7];
  const float* wa  = (const float*)d_in[8];
  const float* wff = (const float*)d_in[9];
  const float* bff = (const float*)d_in[10];
  float* out = (float*)d_out;

  char* ws = (char*)d_ws;
  size_t off = 0;
  auto alloc = [&](size_t bytes) {
    void* p = ws + off;
    off = (off + bytes + 255) & ~(size_t)255;
    return p;
  };
  const int M = 2 * S_TOT;                        // 3456
  bf16*  wf_b   = (bf16*)alloc((size_t)NFUSED * HID * 2);
  bf16*  wcat   = (bf16*)alloc((size_t)HID * KCAT * 2);
  float* bperm  = (float*)alloc((size_t)NFUSED * 4);
  float* scale  = (float*)alloc(2 * HID * 4);
  bf16*  xn     = (bf16*)alloc((size_t)M * HID * 2);
  float* ctab   = (float*)alloc((size_t)S_TOT * ROT * 4);
  float* stab   = (float*)alloc((size_t)S_TOT * ROT * 4);
  bf16*  qkvb   = (bf16*)alloc((size_t)M * NQKV * 2);
  bf16*  qrb    = (bf16*)alloc((size_t)24 * S_TOT * HDIM * 2);
  bf16*  krb    = (bf16*)alloc((size_t)24 * S_TOT * HDIM * 2);
  bf16*  vtb    = (bf16*)alloc((size_t)24 * HDIM * S_TOT * 2);
  bf16*  acat   = (bf16*)alloc((size_t)M * KCAT * 2);     // [att | ff_act]
  if (off > ws_size) return;  // workspace too small -> loud failure

  const int LDS_QKV = 2 * 8192 + 2 * 192 * 32 * 2;        // 40960
  const int LDS_MRG = 2 * 16384 + 2 * 8192;               // 49152 -> 3 blocks/CU
  hipFuncSetAttribute((const void*)k_gemmF, hipFuncAttributeMaxDynamicSharedMemorySize, LDS_QKV);
  hipFuncSetAttribute((const void*)k_gemmO, hipFuncAttributeMaxDynamicSharedMemorySize, LDS_MRG);

  k_conv<<<(NFUSED * HID + 255) / 256, 256, 0, stream>>>(wf, wa, wff, bfu, wf_b, wcat, bperm);
  k_rms<<<2 * HID, 256, 0, stream>>>(x, n1w, scale);
  k_xpose<<<dim3(S_TOT / 32, HID / 32, 2), 256, 0, stream>>>(x, scale, xn);
  k_rope<<<(S_TOT * ROT + 255) / 256, 256, 0, stream>>>(ctab, stab);
  k_gemmF<<<(M / 128) * (NFUSED / 192), 256, LDS_QKV, stream>>>(
      xn, wf_b, bperm, acat, qkvb, M, NFUSED, HID);
  k_qkv<<<M, 256, 0, stream>>>(qkvb, ctab, stab, qg, qb, kg, kb, qrb, krb, vtb);
  k_attn<<<648, 256, 0, stream>>>(qrb, krb, vtb, acat);
  k_gemmO<<<(M / 128) * (HID / 64), 256, LDS_MRG, stream>>>(
      acat, wcat, bff, out, x, M, HID, KCAT);
}

// Round 23
// 139.762 us; speedup vs baseline: 1.0111x; 1.0111x over previous
//
#include <hip/hip_runtime.h>

using bf16 = __bf16;
typedef __attribute__((ext_vector_type(8))) __bf16 bf16x8;
typedef __attribute__((ext_vector_type(4))) float f32x4;

#define HID    768
#define S_TOT  1728
#define MLP_   3072
#define NFUSED 5376   /* MLP + 3*HID */
#define HEADS  12
#define HDIM   64
#define ROT    48
#define KCAT   2304   /* HID + MLP/2 : merged attn-out/FF GEMM K */
#define NQKV   2304   /* q|k|v compact buffer width */

// ---- async global->LDS, 16B per lane. LDS dst is wave-uniform base; HW adds lane*16.
__device__ __forceinline__ void gload16(const void* g, void* l) {
  __builtin_amdgcn_global_load_lds((__attribute__((address_space(1))) void*)g,
                                   (__attribute__((address_space(3))) void*)l,
                                   16, 0, 0);
}

// native 2^x : raw v_exp_f32 (exp2f w/o fast-math takes OCML's correction path, ~15 cyc extra)
__device__ __forceinline__ float fexp2(float x) {
  float r; asm("v_exp_f32 %0, %1" : "=v"(r) : "v"(x)); return r;
}

// pack two f32 -> 2 bf16 in one u32 (lo = src0)
__device__ __forceinline__ unsigned int cvtpk(float lo, float hi) {
  unsigned int r;
  asm("v_cvt_pk_bf16_f32 %0, %1, %2" : "=v"(r) : "v"(lo), "v"(hi));
  return r;
}

__device__ __forceinline__ float wsum64(float v) {
  #pragma unroll
  for (int d = 32; d; d >>= 1) v += __shfl_xor(v, d);
  return v;
}

// ---------------- weights fp32 -> bf16, x/gate-interleaved + K-concat ----------------
__global__ __launch_bounds__(256) void k_conv(const float* __restrict__ wf,
    const float* __restrict__ wa, const float* __restrict__ wff,
    const float* __restrict__ bfu,
    bf16* __restrict__ owf, bf16* __restrict__ wcat, float* __restrict__ bperm) {
  int i = blockIdx.x * 256 + threadIdx.x;
  const int nf = NFUSED * HID, na = HID * HID, nff = HID * (MLP_ / 2);
  auto perm = [](int o) {
    if (o < 1536) return (o >> 4) * 32 + (o & 15);
    if (o < 3072) { int g = o - 1536; return (g >> 4) * 32 + 16 + (g & 15); }
    return o;
  };
  if (i < nf) {
    int o = i / HID, c = i % HID;
    owf[(size_t)perm(o) * HID + c] = (bf16)wf[i];
  }
  if (i < NFUSED) bperm[perm(i)] = bfu[i];
  if (i < na)  wcat[(i / HID) * KCAT + (i % HID)] = (bf16)wa[i];
  if (i < nff) wcat[(i / (MLP_ / 2)) * KCAT + HID + (i % (MLP_ / 2))] = (bf16)wff[i];
}

// ---------------- per-(b,c) RMS over spatial ----------------
__global__ __launch_bounds__(256) void k_rms(const float* __restrict__ x,
    const float* __restrict__ w, float* __restrict__ scale) {
  int bc = blockIdx.x;                       // 0..1535
  const float* xp = x + (size_t)bc * S_TOT;
  float s = 0.f;
  for (int i = threadIdx.x; i < S_TOT; i += 256) { float v = xp[i]; s += v * v; }
  s = wsum64(s);
  __shared__ float red[4];
  int lane = threadIdx.x & 63, wv = threadIdx.x >> 6;
  if (lane == 0) red[wv] = s;
  __syncthreads();
  if (threadIdx.x == 0) {
    float t = red[0] + red[1] + red[2] + red[3];
    scale[bc] = w[bc % HID] * rsqrtf(t * (1.f / S_TOT) + 1e-6f);
  }
}

// ---------------- normalize + transpose (B,C,S) -> (B*S, C) bf16 ----------------
__global__ __launch_bounds__(256) void k_xpose(const float* __restrict__ x,
    const float* __restrict__ scale, bf16* __restrict__ xn) {
  __shared__ float t[32][33];
  int b = blockIdx.z, st = blockIdx.x * 32, ct = blockIdx.y * 32;
  int tx = threadIdx.x & 31, ty = threadIdx.x >> 5;
  #pragma unroll
  for (int i = 0; i < 4; ++i) {
    int c = ct + ty + i * 8;
    t[ty + i * 8][tx] = x[((size_t)b * HID + c) * S_TOT + st + tx] * scale[b * HID + c];
  }
  __syncthreads();
  #pragma unroll
  for (int i = 0; i < 4; ++i) {
    int s = st + ty + i * 8;
    xn[((size_t)b * S_TOT + s) * HID + ct + tx] = (bf16)t[tx][ty + i * 8];
  }
}

// ---------------- RoPE cos/sin tables (S,48) ----------------
__global__ __launch_bounds__(256) void k_rope(float* __restrict__ ct, float* __restrict__ st) {
  int i = blockIdx.x * 256 + threadIdx.x;
  if (i >= S_TOT * ROT) return;
  int s = i / ROT, j = i % ROT;
  int axis = j >> 4, pr = (j & 15) >> 1;
  float base = 3.14159265358979323846f * (1.f + pr * (127.f / 7.f));
  int coord = axis == 0 ? (s / 144) : axis == 1 ? ((s / 12) % 12) : (s % 12);
  float pos = -1.f + coord * (2.f / 11.f);
  float f = pos * base;
  ct[i] = cosf(f); st[i] = sinf(f);
}

// ---------------- QKV GEMM (ACCEPTED, R14/R16-proven): BM=128, BN=192, BK=32, 2-buf ----------------
// stage(t+1)-at-top + counted vmcnt(5). Structural plateau at MfmaUtil~23%:
// register shaves (x2), 3-buf pipeline, and BN=128 all failed to improve it
// (R13/R15/R17) -- accepted at ~46us. T2 swizzle, T1 n-major XCD chunking,
// fused SiLU epilogue (x/gate interleaved weights), bfr-singly inner loop.
__global__ __launch_bounds__(256, 3) void k_gemmF(const bf16* __restrict__ A,
    const bf16* __restrict__ Bw, const float* __restrict__ bias,
    bf16* __restrict__ acat, bf16* __restrict__ qkvb, int M, int N, int K) {
  extern __shared__ __align__(16) char smem[];
  bf16* aL = (bf16*)smem;                       // 2 bufs x 128x32
  bf16* bL = (bf16*)(smem + 2 * 8192);          // 2 bufs x 192x32
  constexpr int BN = 192, NT = 6;
  const int nT = K / 32;
  int nwg = gridDim.x;
  int cq = nwg >> 3, crr = nwg & 7;
  int xcd = blockIdx.x & 7, pos = blockIdx.x >> 3;
  int idx = (xcd < crr ? xcd * (cq + 1) : crr * (cq + 1) + (xcd - crr) * cq) + pos;
  int nmt = M / 128;
  int n0 = (idx / nmt) * BN, m0 = (idx % nmt) * 128;
  int lane = threadIdx.x & 63, wv = threadIdx.x >> 6;
  int wm = (wv >> 1) * 64, wn = (wv & 1) * (BN / 2);
  int arow = lane >> 2;
  int acs = ((lane & 3) ^ ((lane >> 3) & 3)) * 8;   // T2 pre-swizzled source chunk
  int r16 = lane & 15, g8 = (lane >> 4) * 8;
  int swz = ((r16 >> 1) & 3) << 3;                  // T2 read-side XOR
  const bf16* Ag = A + (size_t)m0 * K;
  const bf16* Bg = Bw + (size_t)n0 * K;
  auto stage = [&](int p, int t) {
    int kk = t * 32;
    #pragma unroll
    for (int i = 0; i < 2; ++i) {
      int rb = wv * 32 + i * 16;
      gload16(Ag + (size_t)(rb + arow) * K + kk + acs, aL + p * 4096 + rb * 32);
    }
    #pragma unroll
    for (int i = 0; i < 3; ++i) {
      int rb = wv * 48 + i * 16;
      gload16(Bg + (size_t)(rb + arow) * K + kk + acs, bL + p * (BN * 32) + rb * 32);
    }
  };
  f32x4 acc[4][NT] = {};
  int p = 0;
  stage(0, 0);
  for (int t = 0; t < nT; ++t) {
    if (t + 1 < nT) {
      stage(p ^ 1, t + 1);
      asm volatile("s_waitcnt vmcnt(5)\ns_barrier" ::: "memory");
    } else {
      asm volatile("s_waitcnt vmcnt(0)\ns_barrier" ::: "memory");
    }
    bf16x8 af[4];
    #pragma unroll
    for (int mi = 0; mi < 4; ++mi)
      af[mi] = *(const bf16x8*)(aL + p * 4096 + (wm + mi * 16 + r16) * 32 + (g8 ^ swz));
    __builtin_amdgcn_s_setprio(1);
    #pragma unroll
    for (int ni = 0; ni < NT; ++ni) {
      bf16x8 bfr = *(const bf16x8*)(bL + p * (BN * 32) + (wn + ni * 16 + r16) * 32 + (g8 ^ swz));
      #pragma unroll
      for (int mi = 0; mi < 4; ++mi)
        acc[mi][ni] = __builtin_amdgcn_mfma_f32_16x16x32_bf16(af[mi], bfr, acc[mi][ni], 0, 0, 0);
    }
    __builtin_amdgcn_s_setprio(0);
    asm volatile("s_barrier" ::: "memory");   // readers done before restage
    p ^= 1;
  }
  int cr = (lane >> 4) * 4;
  if (n0 < MLP_) {
    // interleaved x/gate: frag pair (2p, 2p+1) -> 16 ff channels each
    #pragma unroll
    for (int pp = 0; pp < 3; ++pp) {
      int base = n0 + wn + pp * 32;
      int ch = (base >> 5) * 16 + r16;
      float bx = bias[base + r16], bg = bias[base + 16 + r16];
      #pragma unroll
      for (int mi = 0; mi < 4; ++mi)
        #pragma unroll
        for (int j = 0; j < 4; ++j) {
          int row = m0 + wm + mi * 16 + cr + j;
          float xv = acc[mi][2 * pp][j] + bx;
          float gv = acc[mi][2 * pp + 1][j] + bg;
          float sg = gv / (1.f + fexp2(gv * -1.442695041f));
          acat[(size_t)row * KCAT + HID + ch] = (bf16)(sg * xv);
        }
    }
  } else {
    #pragma unroll
    for (int mi = 0; mi < 4; ++mi)
      #pragma unroll
      for (int ni = 0; ni < NT; ++ni) {
        int col = n0 + wn + ni * 16 + r16;
        float bv = bias[col];
        #pragma unroll
        for (int j = 0; j < 4; ++j) {
          int row = m0 + wm + mi * 16 + cr + j;
          qkvb[(size_t)row * NQKV + (col - MLP_)] = (bf16)(acc[mi][ni][j] + bv);
        }
      }
  }
}

// ---------------- merged GEMM (R18-proven): BM=128, BN=64, BK=64, 2-buf, 36 iters ----------------
// BN=32 variant REGRESSED (R20) -- BN=64 is the accepted local optimum.
__global__ __launch_bounds__(256, 3) void k_gemmO(const bf16* __restrict__ A,
    const bf16* __restrict__ Bw, const float* __restrict__ bias,
    float* __restrict__ Out, const float* __restrict__ X, int M, int N, int K) {
  extern __shared__ __align__(16) char smem[];
  bf16* aL = (bf16*)smem;                       // 2 bufs x 128x64 (16384 B each)
  bf16* bL = (bf16*)(smem + 2 * 16384);         // 2 bufs x 64x64  (8192 B each)
  const int nT = K / 64;                        // 36
  int nwg = gridDim.x;
  int cq = nwg >> 3, crr = nwg & 7;
  int xcd = blockIdx.x & 7, pos = blockIdx.x >> 3;
  int idx = (xcd < crr ? xcd * (cq + 1) : crr * (cq + 1) + (xcd - crr) * cq) + pos;
  int ntn = N / 64;
  int m0 = (idx / ntn) * 128, n0 = (idx % ntn) * 64;   // m-major (A-panel locality)
  int lane = threadIdx.x & 63, wv = threadIdx.x >> 6;
  int wm = (wv >> 1) * 64, wn = (wv & 1) * 32;
  int rg = lane >> 3, ch = lane & 7;            // staging: 8 rows x 8 chunks per 1KB issue
  int scs = (ch ^ rg) * 8;                      // pre-swizzled source elem offset
  int r16 = lane & 15, g8 = (lane >> 4) * 8;    // fragment addressing
  const bf16* Ag = A + (size_t)m0 * K;
  const bf16* Bg = Bw + (size_t)n0 * K;
  auto stage = [&](int p, int t) {
    int kk = t * 64;
    #pragma unroll
    for (int i = 0; i < 4; ++i) {
      int rb = wv * 32 + i * 8;
      gload16(Ag + (size_t)(rb + rg) * K + kk + scs, aL + p * 8192 + rb * 64);
    }
    #pragma unroll
    for (int i = 0; i < 2; ++i) {
      int rb = wv * 16 + i * 8;
      gload16(Bg + (size_t)(rb + rg) * K + kk + scs, bL + p * 4096 + rb * 64);
    }
  };
  f32x4 acc[4][2] = {};
  int p = 0;
  stage(0, 0);
  for (int t = 0; t < nT; ++t) {
    if (t + 1 < nT) {
      stage(p ^ 1, t + 1);
      asm volatile("s_waitcnt vmcnt(6)\ns_barrier" ::: "memory");
    } else {
      asm volatile("s_waitcnt vmcnt(0)\ns_barrier" ::: "memory");
    }
    bf16x8 af[4][2], bfr[2][2];
    #pragma unroll
    for (int kc = 0; kc < 2; ++kc) {
      int ce = ((kc * 4 + (lane >> 4)) ^ (r16 & 7)) * 8;   // swizzled chunk, elems
      #pragma unroll
      for (int mi = 0; mi < 4; ++mi)
        af[mi][kc] = *(const bf16x8*)(aL + p * 8192 + (wm + mi * 16 + r16) * 64 + ce);
      #pragma unroll
      for (int ni = 0; ni < 2; ++ni)
        bfr[ni][kc] = *(const bf16x8*)(bL + p * 4096 + (wn + ni * 16 + r16) * 64 + ce);
    }
    __builtin_amdgcn_s_setprio(1);
    #pragma unroll
    for (int kc = 0; kc < 2; ++kc)
      #pragma unroll
      for (int mi = 0; mi < 4; ++mi)
        #pragma unroll
        for (int ni = 0; ni < 2; ++ni)
          acc[mi][ni] = __builtin_amdgcn_mfma_f32_16x16x32_bf16(af[mi][kc], bfr[ni][kc], acc[mi][ni], 0, 0, 0);
    __builtin_amdgcn_s_setprio(0);
    asm volatile("s_barrier" ::: "memory");
    p ^= 1;
  }
  // transpose via padded LDS, then coalesced store along s with residual
  int cr = (lane >> 4) * 4;
  float* tb = (float*)smem;                    // [64][stride 129]
  __syncthreads();
  #pragma unroll
  for (int mi = 0; mi < 4; ++mi)
    #pragma unroll
    for (int ni = 0; ni < 2; ++ni) {
      int c = wn + ni * 16 + r16;
      float bv = bias[n0 + c];
      #pragma unroll
      for (int j = 0; j < 4; ++j)
        tb[c * 129 + wm + mi * 16 + cr + j] = acc[mi][ni][j] + bv;
    }
  __syncthreads();
  for (int ci = 0; ci < 16; ++ci) {
    int c = wv * 16 + ci;
    #pragma unroll
    for (int si = 0; si < 2; ++si) {
      int r = si * 64 + lane;
      int m = m0 + r;
      int bb = (m >= S_TOT) ? 1 : 0;
      size_t oidx = ((size_t)bb * HID + n0 + c) * S_TOT + (m - bb * S_TOT);
      Out[oidx] = tb[c * 129 + r] + X[oidx];
    }
  }
}

// ---------------- per-head LN + RoPE on q,k; v -> transposed layout ----------------
// q pre-scaled by (1/sqrt(64)) * log2(e) so attention softmax can use exp2.
// V columns within each 64-key tile are stored k-PERMUTED: k' = 4*(k&15) + (k>>4),
// matching k_attn's packed P layout (PV only needs P,V to share one k-ordering).
__global__ __launch_bounds__(256) void k_qkv(const bf16* __restrict__ qkvb,
    const float* __restrict__ ct, const float* __restrict__ st,
    const float* __restrict__ qg, const float* __restrict__ qb,
    const float* __restrict__ kg, const float* __restrict__ kb,
    bf16* __restrict__ qr, bf16* __restrict__ kr, bf16* __restrict__ vt) {
  int bs = blockIdx.x;                    // b*1728 + s
  int b = bs / S_TOT, s = bs % S_TOT;
  int lane = threadIdx.x & 63, wv = threadIdx.x >> 6;
  int d = lane;
  float c = 0.f, sn = 0.f;
  if (d < ROT) { c = ct[s * ROT + d]; sn = st[s * ROT + d]; }
  for (int it = 0; it < 9; ++it) {
    int rr = wv * 9 + it;                 // 0..35 = (tensor, head)
    int t = rr / HEADS, h = rr % HEADS;
    float v = (float)qkvb[(size_t)bs * NQKV + t * HID + h * HDIM + d];
    if (t < 2) {
      float s1 = v, s2 = v * v;           // paired mean/var reduction: one 6-step chain
      #pragma unroll
      for (int dd = 32; dd; dd >>= 1) { s1 += __shfl_xor(s1, dd); s2 += __shfl_xor(s2, dd); }
      float mu = s1 * (1.f / 64);
      float var = s2 * (1.f / 64) - mu * mu;
      float vn = (v - mu) * rsqrtf(var + 1e-5f);
      vn = (t == 0) ? (vn * qg[d] + qb[d]) : (vn * kg[d] + kb[d]);
      float o = vn;
      if (d < ROT) {
        float p = __shfl_xor(vn, 1);
        float rot = (d & 1) ? p : -p;
        o = vn * c + rot * sn;
      }
      if (t == 0) o *= 0.18033688f;       // 0.125 * log2(e)
      bf16* dst = (t == 0) ? qr : kr;
      dst[((size_t)(b * HEADS + h) * S_TOT + s) * HDIM + d] = (bf16)o;
    } else {
      int sl = s & 63;
      int sp = (s & ~63) | ((sl & 15) << 2) | (sl >> 4);   // k' permutation
      vt[((size_t)(b * HEADS + h) * HDIM + d) * S_TOT + sp] = (bf16)v;
    }
  }
}

// ---------------- flash attention (ACCEPTED, R16/R21-proven) ----------------
// 4 waves x 16 q-rows, KV tile 64. T2 swizzle; T5 setprio; static-max exp2 softmax.
// SINGLE barrier per iteration: [vmcnt(0); s_barrier; stage(t+1); compute(buf)].
// T15 2-tile pipeline falsified (R22: +1.2us); barrier-free falsified (R9).
// P->LDS packed (T12-style): k' column permutation shared with V.
__global__ __launch_bounds__(256, 4) void k_attn(const bf16* __restrict__ qr,
    const bf16* __restrict__ kr, const bf16* __restrict__ vt, bf16* __restrict__ acat) {
  __shared__ __align__(16) bf16 kld[2][4096];
  __shared__ __align__(16) bf16 vld[2][4096];     // transposed: [d][k'], swizzled
  __shared__ __align__(16) bf16 pld[4][1024];     // per-wave 16x64 (k' cols), swizzled
  int rid = (blockIdx.x & 7) * 81 + (blockIdx.x >> 3);   // bijective (648 = 8*81)
  int bh = rid / 27, qt = rid % 27;
  int lane = threadIdx.x & 63, wv = threadIdx.x >> 6;
  int r16 = lane & 15, g8 = (lane >> 4) * 8;
  int sw = (r16 & 7) << 3;
  int lsw = (lane & 56) | ((lane ^ (lane >> 3)) & 7);
  const bf16* qbase = qr + ((size_t)bh * S_TOT + qt * 64 + wv * 16) * HDIM;
  bf16x8 qf[2];
  qf[0] = *(const bf16x8*)(qbase + r16 * HDIM + g8);
  qf[1] = *(const bf16x8*)(qbase + r16 * HDIM + 32 + g8);
  asm volatile("s_waitcnt vmcnt(0)" ::: "memory");      // q retired: vmcnt now only tracks stages
  const bf16* kg0 = kr + (size_t)bh * S_TOT * HDIM;
  const bf16* vg0 = vt + (size_t)bh * HDIM * S_TOT;
  auto stage = [&](int buf, int kt) {
    #pragma unroll
    for (int i = 0; i < 2; ++i) {
      int q = wv * 2 + i;
      gload16(kg0 + (size_t)kt * 4096 + q * 512 + lsw * 8, &kld[buf][q * 512]);
      gload16(vg0 + (size_t)(q * 8 + (lane >> 3)) * S_TOT + kt * 64 + (lsw & 7) * 8,
              &vld[buf][q * 512]);
    }
  };
  float l_part[4] = {0.f, 0.f, 0.f, 0.f};         // per-lane partial sums (reduced at end)
  f32x4 acc_o[4] = {};
  stage(0, 0);
  int buf = 0;
  for (int kt = 0; kt < 27; ++kt) {
    asm volatile("s_waitcnt vmcnt(0)\ns_barrier" ::: "memory");   // tile-kt written, all waves
    if (kt + 1 < 27) stage(buf ^ 1, kt + 1);                      // buf^1 last read in iter kt-1
    // ---- QK^T (log2 domain) ----
    f32x4 sa[4];
    __builtin_amdgcn_s_setprio(1);
    #pragma unroll
    for (int nt = 0; nt < 4; ++nt) {
      sa[nt] = f32x4{0.f, 0.f, 0.f, 0.f};
      #pragma unroll
      for (int kc = 0; kc < 2; ++kc) {
        bf16x8 kf = *(const bf16x8*)(&kld[buf][(nt * 16 + r16) * 64 + ((kc * 32 + g8) ^ sw)]);
        sa[nt] = __builtin_amdgcn_mfma_f32_16x16x32_bf16(qf[kc], kf, sa[nt], 0, 0, 0);
      }
    }
    __builtin_amdgcn_s_setprio(0);
    // ---- static-max softmax: P = exp2(logit), accumulate per-lane l ----
    #pragma unroll
    for (int j = 0; j < 4; ++j) {
      #pragma unroll
      for (int nt = 0; nt < 4; ++nt) {
        float pv = fexp2(sa[nt][j]);
        sa[nt][j] = pv;
        l_part[j] += pv;
      }
    }
    // ---- P -> LDS: k' columns 4*r16..4*r16+3, packed b64 writes (swizzled) ----
    #pragma unroll
    for (int j = 0; j < 4; ++j) {
      int rr = (lane >> 4) * 4 + j;
      unsigned int pa = cvtpk(sa[0][j], sa[1][j]);
      unsigned int pb = cvtpk(sa[2][j], sa[3][j]);
      unsigned long long pk = (unsigned long long)pa | ((unsigned long long)pb << 32);
      int off = rr * 64 + ((4 * r16) ^ ((rr & 7) << 3));
      *(unsigned long long*)(&pld[wv][off]) = pk;
    }
    // ---- PV (k' ordering shared by P and V) ----
    __builtin_amdgcn_s_setprio(1);
    #pragma unroll
    for (int nt = 0; nt < 4; ++nt)
      #pragma unroll
      for (int kc = 0; kc < 2; ++kc) {
        bf16x8 pf = *(const bf16x8*)(&pld[wv][r16 * 64 + ((kc * 32 + g8) ^ sw)]);
        bf16x8 vf = *(const bf16x8*)(&vld[buf][(nt * 16 + r16) * 64 + ((kc * 32 + g8) ^ sw)]);
        acc_o[nt] = __builtin_amdgcn_mfma_f32_16x16x32_bf16(pf, vf, acc_o[nt], 0, 0, 0);
      }
    __builtin_amdgcn_s_setprio(0);
    buf ^= 1;
  }
  int b = bh / HEADS, h = bh % HEADS;
  #pragma unroll
  for (int j = 0; j < 4; ++j) {
    float l = l_part[j];
    #pragma unroll
    for (int dd = 1; dd < 16; dd <<= 1) l += __shfl_xor(l, dd);
    float inv = 1.f / l;
    int s = qt * 64 + wv * 16 + (lane >> 4) * 4 + j;
    #pragma unroll
    for (int nt = 0; nt < 4; ++nt)
      acat[((size_t)b * S_TOT + s) * KCAT + h * HDIM + nt * 16 + r16] = (bf16)(acc_o[nt][j] * inv);
  }
}

extern "C" void kernel_launch(void* const* d_in, const int* in_sizes, int n_in,
                              void* d_out, int out_size, void* d_ws, size_t ws_size,
                              hipStream_t stream) {
  const float* x   = (const float*)d_in[0];
  const float* n1w = (const float*)d_in[1];
  const float* wf  = (const float*)d_in[2];
  const float* bfu = (const float*)d_in[3];
  const float* qg  = (const float*)d_in[4];
  const float* qb  = (const float*)d_in[5];
  const float* kg  = (const float*)d_in[6];
  const float* kb  = (const float*)d_in[7];
  const float* wa  = (const float*)d_in[8];
  const float* wff = (const float*)d_in[9];
  const float* bff = (const float*)d_in[10];
  float* out = (float*)d_out;

  char* ws = (char*)d_ws;
  size_t off = 0;
  auto alloc = [&](size_t bytes) {
    void* p = ws + off;
    off = (off + bytes + 255) & ~(size_t)255;
    return p;
  };
  const int M = 2 * S_TOT;                        // 3456
  bf16*  wf_b   = (bf16*)alloc((size_t)NFUSED * HID * 2);
  bf16*  wcat   = (bf16*)alloc((size_t)HID * KCAT * 2);
  float* bperm  = (float*)alloc((size_t)NFUSED * 4);
  float* scale  = (float*)alloc(2 * HID * 4);
  bf16*  xn     = (bf16*)alloc((size_t)M * HID * 2);
  float* ctab   = (float*)alloc((size_t)S_TOT * ROT * 4);
  float* stab   = (float*)alloc((size_t)S_TOT * ROT * 4);
  bf16*  qkvb   = (bf16*)alloc((size_t)M * NQKV * 2);
  bf16*  qrb    = (bf16*)alloc((size_t)24 * S_TOT * HDIM * 2);
  bf16*  krb    = (bf16*)alloc((size_t)24 * S_TOT * HDIM * 2);
  bf16*  vtb    = (bf16*)alloc((size_t)24 * HDIM * S_TOT * 2);
  bf16*  acat   = (bf16*)alloc((size_t)M * KCAT * 2);     // [att | ff_act]
  if (off > ws_size) return;  // workspace too small -> loud failure

  const int LDS_QKV = 2 * 8192 + 2 * 192 * 32 * 2;        // 40960
  const int LDS_MRG = 2 * 16384 + 2 * 8192;               // 49152 -> 3 blocks/CU
  hipFuncSetAttribute((const void*)k_gemmF, hipFuncAttributeMaxDynamicSharedMemorySize, LDS_QKV);
  hipFuncSetAttribute((const void*)k_gemmO, hipFuncAttributeMaxDynamicSharedMemorySize, LDS_MRG);

  k_conv<<<(NFUSED * HID + 255) / 256, 256, 0, stream>>>(wf, wa, wff, bfu, wf_b, wcat, bperm);
  k_rms<<<2 * HID, 256, 0, stream>>>(x, n1w, scale);
  k_xpose<<<dim3(S_TOT / 32, HID / 32, 2), 256, 0, stream>>>(x, scale, xn);
  k_rope<<<(S_TOT * ROT + 255) / 256, 256, 0, stream>>>(ctab, stab);
  k_gemmF<<<(M / 128) * (NFUSED / 192), 256, LDS_QKV, stream>>>(
      xn, wf_b, bperm, acat, qkvb, M, NFUSED, HID);
  k_qkv<<<M, 256, 0, stream>>>(qkvb, ctab, stab, qg, qb, kg, kb, qrb, krb, vtb);
  k_attn<<<648, 256, 0, stream>>>(qrb, krb, vtb, acat);
  k_gemmO<<<(M / 128) * (HID / 64), 256, LDS_MRG, stream>>>(
      acat, wcat, bff, out, x, M, HID, KCAT);
}